// Round 1
// baseline (174.971 us; speedup 1.0000x reference)
//
#include <hip/hip_runtime.h>
#include <hip/hip_bf16.h>

#define HDIM 1024
#define SEQ 2048
#define BATCH 16
#define M_TOT (SEQ*BATCH)   // 32768
#define NBLK 8              // N split into 8 chunks of 128
#define BM 128
#define BN 128
#define BK 32
#define LDT 40              // padded LDS row stride (elems): 80B -> 2-way bank alias (free)

typedef __attribute__((ext_vector_type(8))) short short8;
typedef __attribute__((ext_vector_type(4))) float f32x4;

static __device__ __forceinline__ unsigned short f2bf(float f) {
    unsigned int x = __float_as_uint(f);
    unsigned int r = (x + 0x7FFFu + ((x >> 16) & 1u)) >> 16;  // RNE
    return (unsigned short)r;
}

// ---------------- kernel 1: q[b][k] = sum_h hidden[b][h]*Wh[k][h] + attn_b[k] ----------------
__global__ __launch_bounds__(256) void qk_kernel(const float* __restrict__ hidden,
                                                 const float* __restrict__ attn_w,
                                                 const float* __restrict__ attn_b,
                                                 float* __restrict__ q) {
    int k = blockIdx.x;               // 0..1023
    int tid = threadIdx.x;            // 256
    const float* w = attn_w + (size_t)k * (2 * HDIM);  // Wh row k
    float p[BATCH];
#pragma unroll
    for (int b = 0; b < BATCH; b++) p[b] = 0.f;
    for (int h = tid; h < HDIM; h += 256) {
        float wv = w[h];
#pragma unroll
        for (int b = 0; b < BATCH; b++) p[b] += hidden[b * HDIM + h] * wv;
    }
#pragma unroll
    for (int b = 0; b < BATCH; b++) {
        for (int off = 32; off; off >>= 1) p[b] += __shfl_down(p[b], off);
    }
    __shared__ float red[4][BATCH];
    int lane = tid & 63, wid = tid >> 6;
    if (lane == 0) {
#pragma unroll
        for (int b = 0; b < BATCH; b++) red[wid][b] = p[b];
    }
    __syncthreads();
    if (tid < BATCH) {
        float s = red[0][tid] + red[1][tid] + red[2][tid] + red[3][tid] + attn_b[k];
        q[(size_t)tid * HDIM + k] = s;   // q[b][k]
    }
}

// ---------------- kernel 2: We fp32 -> bf16, layout web[n][h] (row-major 1024x1024) ----------------
__global__ __launch_bounds__(256) void conv_kernel(const float* __restrict__ attn_w,
                                                   __hip_bfloat16* __restrict__ web) {
    size_t i0 = ((size_t)blockIdx.x * 256 + threadIdx.x) * 8;
    int n = (int)(i0 >> 10);
    int h = (int)(i0 & 1023);
    const float4* src = reinterpret_cast<const float4*>(attn_w + (size_t)n * (2 * HDIM) + HDIM + h);
    float4 a = src[0], b = src[1];
    union { unsigned short u[8]; short8 v; } cv;
    cv.u[0] = f2bf(a.x); cv.u[1] = f2bf(a.y); cv.u[2] = f2bf(a.z); cv.u[3] = f2bf(a.w);
    cv.u[4] = f2bf(b.x); cv.u[5] = f2bf(b.y); cv.u[6] = f2bf(b.z); cv.u[7] = f2bf(b.w);
    *reinterpret_cast<short8*>((unsigned short*)web + i0) = cv.v;
}

// ---------------- kernel 3: fused GEMM + tanh + score-dot partials ----------------
// C[m][k] = sum_h enc[m][h]*We[k][h]; part[bn][m] = sum_{k in chunk} score_w[k]*tanh(q[b][k]+C[m][k])
__global__ __launch_bounds__(256) void gemm_kernel(const float* __restrict__ enc,
                                                   const __hip_bfloat16* __restrict__ web,
                                                   const float* __restrict__ q,
                                                   const float* __restrict__ score_w,
                                                   float* __restrict__ part) {
    __shared__ __align__(16) __hip_bfloat16 As[2][BM * LDT];
    __shared__ __align__(16) __hip_bfloat16 Bs[2][BM * LDT];
    __shared__ float q_lds[BATCH][BN];
    __shared__ float sc_lds[BN];
    __shared__ float eng[2][BM];

    int tid = threadIdx.x;
    int lane = tid & 63;
    int wid = tid >> 6;
    int wr = wid >> 1, wc = wid & 1;
    int bm = blockIdx.x, bn = blockIdx.y;
    int m0 = bm * BM, n0 = bn * BN;

    int srow = tid >> 1;     // 0..127
    int shalf = tid & 1;     // 0..1
    const float* gA = enc + (size_t)(m0 + srow) * HDIM + shalf * 16;
    const __hip_bfloat16* gB = web + (size_t)(n0 + srow) * HDIM + shalf * 16;

    float4 a0, a1, a2, a3;
    short8 b0, b1;
    f32x4 acc[4][4];
#pragma unroll
    for (int i = 0; i < 4; i++)
#pragma unroll
        for (int j = 0; j < 4; j++) acc[i][j] = (f32x4)0.f;

    auto LOAD = [&](int kt) {
        const float4* pa = reinterpret_cast<const float4*>(gA + kt * BK);
        a0 = pa[0]; a1 = pa[1]; a2 = pa[2]; a3 = pa[3];
        const short8* pb = reinterpret_cast<const short8*>(gB + kt * BK);
        b0 = pb[0]; b1 = pb[1];
    };

    auto STORE = [&](int buf) {
        union { unsigned short u[8]; short8 v; } u0, u1;
        u0.u[0] = f2bf(a0.x); u0.u[1] = f2bf(a0.y); u0.u[2] = f2bf(a0.z); u0.u[3] = f2bf(a0.w);
        u0.u[4] = f2bf(a1.x); u0.u[5] = f2bf(a1.y); u0.u[6] = f2bf(a1.z); u0.u[7] = f2bf(a1.w);
        u1.u[0] = f2bf(a2.x); u1.u[1] = f2bf(a2.y); u1.u[2] = f2bf(a2.z); u1.u[3] = f2bf(a2.w);
        u1.u[4] = f2bf(a3.x); u1.u[5] = f2bf(a3.y); u1.u[6] = f2bf(a3.z); u1.u[7] = f2bf(a3.w);
        __hip_bfloat16* da = &As[buf][srow * LDT + shalf * 16];
        *reinterpret_cast<short8*>(da) = u0.v;
        *reinterpret_cast<short8*>(da + 8) = u1.v;
        __hip_bfloat16* db = &Bs[buf][srow * LDT + shalf * 16];
        *reinterpret_cast<short8*>(db) = b0;
        *reinterpret_cast<short8*>(db + 8) = b1;
    };

    auto COMPUTE = [&](int buf) {
        short8 af[4], bfg[4];
        int rA = wr * 64 + (lane & 15);
        int rB = wc * 64 + (lane & 15);
        int ko = (lane >> 4) * 8;
#pragma unroll
        for (int i = 0; i < 4; i++) af[i] = *reinterpret_cast<const short8*>(&As[buf][(rA + i * 16) * LDT + ko]);
#pragma unroll
        for (int j = 0; j < 4; j++) bfg[j] = *reinterpret_cast<const short8*>(&Bs[buf][(rB + j * 16) * LDT + ko]);
#pragma unroll
        for (int i = 0; i < 4; i++)
#pragma unroll
            for (int j = 0; j < 4; j++)
                acc[i][j] = __builtin_amdgcn_mfma_f32_16x16x32_bf16(af[i], bfg[j], acc[i][j], 0, 0, 0);
    };

    LOAD(0);
    STORE(0);
    __syncthreads();
    const int NK = HDIM / BK;  // 32
    for (int kt = 0; kt < NK; ++kt) {
        int cur = kt & 1;
        if (kt + 1 < NK) LOAD(kt + 1);
        COMPUTE(cur);
        if (kt + 1 < NK) STORE(cur ^ 1);
        __syncthreads();
    }

    // epilogue: stage q-slice and score-slice
    {
        int idx = tid * 8;            // 0..2047
        int qb = idx >> 7, kl = idx & 127;
        const float4* src = reinterpret_cast<const float4*>(q + (size_t)qb * HDIM + n0 + kl);
        float4 v0 = src[0], v1 = src[1];
        *reinterpret_cast<float4*>(&q_lds[qb][kl]) = v0;
        *reinterpret_cast<float4*>(&q_lds[qb][kl + 4]) = v1;
        if (tid < BN) sc_lds[tid] = score_w[n0 + tid];
    }
    __syncthreads();

    int cshift = lane >> 4;  // 0..3
#pragma unroll
    for (int mi = 0; mi < 4; ++mi) {
#pragma unroll
        for (int r = 0; r < 4; ++r) {
            int b = cshift * 4 + r;  // row-within-16 == batch index
            float s = 0.f;
#pragma unroll
            for (int j = 0; j < 4; ++j) {
                int kl = wc * 64 + j * 16 + (lane & 15);
                float v = acc[mi][j][r] + q_lds[b][kl];
                float t = 1.f - 2.f / (__expf(2.f * v) + 1.f);  // tanh(v)
                s += sc_lds[kl] * t;
            }
            for (int off = 1; off < 16; off <<= 1) s += __shfl_xor(s, off);
            if ((lane & 15) == 0) eng[wc][wr * 64 + mi * 16 + b] = s;
        }
    }
    __syncthreads();
    if (tid < BM) part[(size_t)bn * M_TOT + m0 + tid] = eng[0][tid] + eng[1][tid];
}

// ---------------- kernel 4: reduce partials + mask + softmax over S ----------------
__global__ __launch_bounds__(256) void softmax_kernel(const float* __restrict__ part,
                                                      const int* __restrict__ mask,
                                                      float* __restrict__ out) {
    int b = blockIdx.x;
    int tid = threadIdx.x;
    __shared__ float e_lds[SEQ];
    __shared__ float red[4], red2[4];
    int lane = tid & 63, wid = tid >> 6;
    float lmax = -3.4e38f;
    for (int it = 0; it < SEQ / 256; ++it) {
        int s = it * 256 + tid;
        size_t m = (size_t)s * BATCH + b;
        float e = 0.f;
#pragma unroll
        for (int c = 0; c < NBLK; c++) e += part[(size_t)c * M_TOT + m];
        if (mask[(size_t)b * SEQ + s]) e = -1e12f;
        e_lds[s] = e;
        lmax = fmaxf(lmax, e);
    }
    for (int off = 32; off; off >>= 1) lmax = fmaxf(lmax, __shfl_xor(lmax, off));
    if (lane == 0) red[wid] = lmax;
    __syncthreads();
    float gmax = fmaxf(fmaxf(red[0], red[1]), fmaxf(red[2], red[3]));
    float lsum = 0.f;
    for (int it = 0; it < SEQ / 256; ++it) {
        int s = it * 256 + tid;
        float p = __expf(e_lds[s] - gmax);
        e_lds[s] = p;
        lsum += p;
    }
    for (int off = 32; off; off >>= 1) lsum += __shfl_xor(lsum, off);
    if (lane == 0) red2[wid] = lsum;
    __syncthreads();
    float inv = 1.f / (red2[0] + red2[1] + red2[2] + red2[3]);
    for (int it = 0; it < SEQ / 256; ++it) {
        int s = it * 256 + tid;
        out[(size_t)b * SEQ + s] = e_lds[s] * inv;
    }
}

extern "C" void kernel_launch(void* const* d_in, const int* in_sizes, int n_in,
                              void* d_out, int out_size, void* d_ws, size_t ws_size,
                              hipStream_t stream) {
    const float* hidden   = (const float*)d_in[0];
    const float* enc      = (const float*)d_in[1];
    const int*   seq_mask = (const int*)d_in[2];
    const float* attn_w   = (const float*)d_in[3];
    const float* attn_b   = (const float*)d_in[4];
    const float* score_w  = (const float*)d_in[5];
    float* out = (float*)d_out;

    char* ws = (char*)d_ws;
    float* q = (float*)ws;                                        // 16*1024*4 = 64 KB
    __hip_bfloat16* web = (__hip_bfloat16*)(ws + 65536);          // 2 MB
    float* part = (float*)(ws + 65536 + 2 * 1024 * 1024);         // 8*32768*4 = 1 MB

    qk_kernel<<<dim3(HDIM), dim3(256), 0, stream>>>(hidden, attn_w, attn_b, q);
    conv_kernel<<<dim3((HDIM * HDIM) / (8 * 256)), dim3(256), 0, stream>>>(attn_w, web);
    gemm_kernel<<<dim3(M_TOT / BM, NBLK), dim3(256), 0, stream>>>(enc, web, q, score_w, part);
    softmax_kernel<<<dim3(BATCH), dim3(256), 0, stream>>>(part, seq_mask, out);
}

// Round 2
// 162.407 us; speedup vs baseline: 1.0774x; 1.0774x over previous
//
#include <hip/hip_runtime.h>
#include <hip/hip_bf16.h>

#define HDIM 1024
#define SEQ 2048
#define BATCH 16
#define M_TOT (SEQ*BATCH)   // 32768
#define NBLK 8              // N split into 8 chunks of 128
#define BM 128
#define BN 128
#define BK 32
#define NKT (HDIM/BK)       // 32
#define LDT 40              // padded stride for fallback fp32-staging kernel

typedef __attribute__((ext_vector_type(8))) short short8;
typedef __attribute__((ext_vector_type(4))) float f32x4;

typedef const void __attribute__((address_space(1))) gvoid_t;
typedef void __attribute__((address_space(3))) svoid_t;
#define GLD16(gp, lp) __builtin_amdgcn_global_load_lds((gvoid_t*)(gp), (svoid_t*)(lp), 16, 0, 0)

static __device__ __forceinline__ unsigned short f2bf(float f) {
    unsigned int x = __float_as_uint(f);
    unsigned int r = (x + 0x7FFFu + ((x >> 16) & 1u)) >> 16;  // RNE
    return (unsigned short)r;
}

// ---------------- kernel 1: q[b][k] = sum_h hidden[b][h]*Wh[k][h] + attn_b[k] ----------------
__global__ __launch_bounds__(256) void qk_kernel(const float* __restrict__ hidden,
                                                 const float* __restrict__ attn_w,
                                                 const float* __restrict__ attn_b,
                                                 float* __restrict__ q) {
    int k = blockIdx.x;               // 0..1023
    int tid = threadIdx.x;            // 256
    const float* w = attn_w + (size_t)k * (2 * HDIM);  // Wh row k
    float p[BATCH];
#pragma unroll
    for (int b = 0; b < BATCH; b++) p[b] = 0.f;
    for (int h = tid; h < HDIM; h += 256) {
        float wv = w[h];
#pragma unroll
        for (int b = 0; b < BATCH; b++) p[b] += hidden[b * HDIM + h] * wv;
    }
#pragma unroll
    for (int b = 0; b < BATCH; b++) {
        for (int off = 32; off; off >>= 1) p[b] += __shfl_down(p[b], off);
    }
    __shared__ float red[4][BATCH];
    int lane = tid & 63, wid = tid >> 6;
    if (lane == 0) {
#pragma unroll
        for (int b = 0; b < BATCH; b++) red[wid][b] = p[b];
    }
    __syncthreads();
    if (tid < BATCH) {
        float s = red[0][tid] + red[1][tid] + red[2][tid] + red[3][tid] + attn_b[k];
        q[(size_t)tid * HDIM + k] = s;   // q[b][k]
    }
}

// ---------------- kernel 2: We fp32 -> bf16, layout web[n][h] ----------------
__global__ __launch_bounds__(256) void conv_kernel(const float* __restrict__ attn_w,
                                                   __hip_bfloat16* __restrict__ web) {
    size_t i0 = ((size_t)blockIdx.x * 256 + threadIdx.x) * 8;
    int n = (int)(i0 >> 10);
    int h = (int)(i0 & 1023);
    const float4* src = reinterpret_cast<const float4*>(attn_w + (size_t)n * (2 * HDIM) + HDIM + h);
    float4 a = src[0], b = src[1];
    union { unsigned short u[8]; short8 v; } cv;
    cv.u[0] = f2bf(a.x); cv.u[1] = f2bf(a.y); cv.u[2] = f2bf(a.z); cv.u[3] = f2bf(a.w);
    cv.u[4] = f2bf(b.x); cv.u[5] = f2bf(b.y); cv.u[6] = f2bf(b.z); cv.u[7] = f2bf(b.w);
    *reinterpret_cast<short8*>((unsigned short*)web + i0) = cv.v;
}

// ---------------- kernel 2b: enc fp32 -> bf16 (row-major [M_TOT][H]) ----------------
__global__ __launch_bounds__(256) void conv_enc(const float* __restrict__ src,
                                                __hip_bfloat16* __restrict__ dst) {
    size_t i0 = ((size_t)blockIdx.x * 256 + threadIdx.x) * 8;
    const float4* s = reinterpret_cast<const float4*>(src + i0);
    float4 a = s[0], b = s[1];
    union { unsigned short u[8]; short8 v; } cv;
    cv.u[0] = f2bf(a.x); cv.u[1] = f2bf(a.y); cv.u[2] = f2bf(a.z); cv.u[3] = f2bf(a.w);
    cv.u[4] = f2bf(b.x); cv.u[5] = f2bf(b.y); cv.u[6] = f2bf(b.z); cv.u[7] = f2bf(b.w);
    *reinterpret_cast<short8*>((unsigned short*)dst + i0) = cv.v;
}

// ---------------- kernel 3 (fast): bf16 GEMM via global_load_lds + fused tanh/score epilogue ----
__global__ __launch_bounds__(256) void gemm_bf(const __hip_bfloat16* __restrict__ encb,
                                               const __hip_bfloat16* __restrict__ web,
                                               const float* __restrict__ q,
                                               const float* __restrict__ score_w,
                                               float* __restrict__ part) {
    __shared__ __align__(16) __hip_bfloat16 As[2][BM * BK];
    __shared__ __align__(16) __hip_bfloat16 Bs[2][BM * BK];
    __shared__ float q_lds[BATCH][BN];
    __shared__ float sc_lds[BN];
    __shared__ float eng[2][BM];

    int tid = threadIdx.x;
    int lane = tid & 63;
    int wid = tid >> 6;
    int wr = wid >> 1, wc = wid & 1;
    int bn = blockIdx.x, bm = blockIdx.y;
    int m0 = bm * BM, n0 = bn * BN;

    // staging addresses: wave wid covers rows [wid*32, wid*32+32) in two 16-row chunks
    int srow = wid * 32 + (lane >> 2);
    int scol = (lane & 3) * 8;
    const __hip_bfloat16* gA = encb + (size_t)(m0 + srow) * HDIM + scol;
    const __hip_bfloat16* gB = web + (size_t)(n0 + srow) * HDIM + scol;
    unsigned lo = wid * 1024;  // element offset of this wave's LDS chunk

    f32x4 acc[4][4];
#pragma unroll
    for (int i = 0; i < 4; i++)
#pragma unroll
        for (int j = 0; j < 4; j++) acc[i][j] = (f32x4)0.f;

    auto STAGE = [&](int buf, int kt) {
        const __hip_bfloat16* pa = gA + kt * BK;
        const __hip_bfloat16* pb = gB + kt * BK;
        GLD16(pa, &As[buf][lo]);
        GLD16(pa + 16 * HDIM, &As[buf][lo + 512]);
        GLD16(pb, &Bs[buf][lo]);
        GLD16(pb + 16 * HDIM, &Bs[buf][lo + 512]);
    };

    auto COMPUTE = [&](int buf) {
        short8 af[4], bfr[4];
        int rA = wr * 64 + (lane & 15);
        int rB = wc * 64 + (lane & 15);
        int ko = (lane >> 4) * 8;
#pragma unroll
        for (int i = 0; i < 4; i++) af[i] = *reinterpret_cast<const short8*>(&As[buf][(rA + i * 16) * BK + ko]);
#pragma unroll
        for (int j = 0; j < 4; j++) bfr[j] = *reinterpret_cast<const short8*>(&Bs[buf][(rB + j * 16) * BK + ko]);
#pragma unroll
        for (int i = 0; i < 4; i++)
#pragma unroll
            for (int j = 0; j < 4; j++)
                acc[i][j] = __builtin_amdgcn_mfma_f32_16x16x32_bf16(af[i], bfr[j], acc[i][j], 0, 0, 0);
    };

    STAGE(0, 0);
    __syncthreads();
    for (int kt = 0; kt < NKT; ++kt) {
        int cur = kt & 1;
        if (kt + 1 < NKT) STAGE(cur ^ 1, kt + 1);
        COMPUTE(cur);
        __syncthreads();
    }

    // epilogue: stage q-slice and score-slice
    {
        int idx = tid * 8;            // 0..2047
        int qb = idx >> 7, kl = idx & 127;
        const float4* src = reinterpret_cast<const float4*>(q + (size_t)qb * HDIM + n0 + kl);
        float4 v0 = src[0], v1 = src[1];
        *reinterpret_cast<float4*>(&q_lds[qb][kl]) = v0;
        *reinterpret_cast<float4*>(&q_lds[qb][kl + 4]) = v1;
        if (tid < BN) sc_lds[tid] = score_w[n0 + tid];
    }
    __syncthreads();

    int cshift = lane >> 4;  // 0..3
#pragma unroll
    for (int mi = 0; mi < 4; ++mi) {
#pragma unroll
        for (int r = 0; r < 4; ++r) {
            int b = cshift * 4 + r;  // row-within-16 == batch index (M = s*16 + b)
            float s = 0.f;
#pragma unroll
            for (int j = 0; j < 4; ++j) {
                int kl = wc * 64 + j * 16 + (lane & 15);
                float v = acc[mi][j][r] + q_lds[b][kl];
                float t = 1.f - 2.f / (__expf(2.f * v) + 1.f);  // tanh(v)
                s += sc_lds[kl] * t;
            }
            for (int off = 1; off < 16; off <<= 1) s += __shfl_xor(s, off);
            if ((lane & 15) == 0) eng[wc][wr * 64 + mi * 16 + b] = s;
        }
    }
    __syncthreads();
    if (tid < BM) part[(size_t)bn * M_TOT + m0 + tid] = eng[0][tid] + eng[1][tid];
}

// ---------------- kernel 3 (fallback): fp32 reg-staged GEMM (round-1 version) ----------------
__global__ __launch_bounds__(256) void gemm_kernel(const float* __restrict__ enc,
                                                   const __hip_bfloat16* __restrict__ web,
                                                   const float* __restrict__ q,
                                                   const float* __restrict__ score_w,
                                                   float* __restrict__ part) {
    __shared__ __align__(16) __hip_bfloat16 As[2][BM * LDT];
    __shared__ __align__(16) __hip_bfloat16 Bs[2][BM * LDT];
    __shared__ float q_lds[BATCH][BN];
    __shared__ float sc_lds[BN];
    __shared__ float eng[2][BM];

    int tid = threadIdx.x;
    int lane = tid & 63;
    int wid = tid >> 6;
    int wr = wid >> 1, wc = wid & 1;
    int bm = blockIdx.x, bn = blockIdx.y;
    int m0 = bm * BM, n0 = bn * BN;

    int srow = tid >> 1;
    int shalf = tid & 1;
    const float* gA = enc + (size_t)(m0 + srow) * HDIM + shalf * 16;
    const __hip_bfloat16* gB = web + (size_t)(n0 + srow) * HDIM + shalf * 16;

    float4 a0, a1, a2, a3;
    short8 b0, b1;
    f32x4 acc[4][4];
#pragma unroll
    for (int i = 0; i < 4; i++)
#pragma unroll
        for (int j = 0; j < 4; j++) acc[i][j] = (f32x4)0.f;

    auto LOAD = [&](int kt) {
        const float4* pa = reinterpret_cast<const float4*>(gA + kt * BK);
        a0 = pa[0]; a1 = pa[1]; a2 = pa[2]; a3 = pa[3];
        const short8* pb = reinterpret_cast<const short8*>(gB + kt * BK);
        b0 = pb[0]; b1 = pb[1];
    };

    auto STORE = [&](int buf) {
        union { unsigned short u[8]; short8 v; } u0, u1;
        u0.u[0] = f2bf(a0.x); u0.u[1] = f2bf(a0.y); u0.u[2] = f2bf(a0.z); u0.u[3] = f2bf(a0.w);
        u0.u[4] = f2bf(a1.x); u0.u[5] = f2bf(a1.y); u0.u[6] = f2bf(a1.z); u0.u[7] = f2bf(a1.w);
        u1.u[0] = f2bf(a2.x); u1.u[1] = f2bf(a2.y); u1.u[2] = f2bf(a2.z); u1.u[3] = f2bf(a2.w);
        u1.u[4] = f2bf(a3.x); u1.u[5] = f2bf(a3.y); u1.u[6] = f2bf(a3.z); u1.u[7] = f2bf(a3.w);
        __hip_bfloat16* da = &As[buf][srow * LDT + shalf * 16];
        *reinterpret_cast<short8*>(da) = u0.v;
        *reinterpret_cast<short8*>(da + 8) = u1.v;
        __hip_bfloat16* db = &Bs[buf][srow * LDT + shalf * 16];
        *reinterpret_cast<short8*>(db) = b0;
        *reinterpret_cast<short8*>(db + 8) = b1;
    };

    auto COMPUTE = [&](int buf) {
        short8 af[4], bfg[4];
        int rA = wr * 64 + (lane & 15);
        int rB = wc * 64 + (lane & 15);
        int ko = (lane >> 4) * 8;
#pragma unroll
        for (int i = 0; i < 4; i++) af[i] = *reinterpret_cast<const short8*>(&As[buf][(rA + i * 16) * LDT + ko]);
#pragma unroll
        for (int j = 0; j < 4; j++) bfg[j] = *reinterpret_cast<const short8*>(&Bs[buf][(rB + j * 16) * LDT + ko]);
#pragma unroll
        for (int i = 0; i < 4; i++)
#pragma unroll
            for (int j = 0; j < 4; j++)
                acc[i][j] = __builtin_amdgcn_mfma_f32_16x16x32_bf16(af[i], bfg[j], acc[i][j], 0, 0, 0);
    };

    LOAD(0);
    STORE(0);
    __syncthreads();
    for (int kt = 0; kt < NKT; ++kt) {
        int cur = kt & 1;
        if (kt + 1 < NKT) LOAD(kt + 1);
        COMPUTE(cur);
        if (kt + 1 < NKT) STORE(cur ^ 1);
        __syncthreads();
    }

    {
        int idx = tid * 8;
        int qb = idx >> 7, kl = idx & 127;
        const float4* src = reinterpret_cast<const float4*>(q + (size_t)qb * HDIM + n0 + kl);
        float4 v0 = src[0], v1 = src[1];
        *reinterpret_cast<float4*>(&q_lds[qb][kl]) = v0;
        *reinterpret_cast<float4*>(&q_lds[qb][kl + 4]) = v1;
        if (tid < BN) sc_lds[tid] = score_w[n0 + tid];
    }
    __syncthreads();

    int cshift = lane >> 4;
#pragma unroll
    for (int mi = 0; mi < 4; ++mi) {
#pragma unroll
        for (int r = 0; r < 4; ++r) {
            int b = cshift * 4 + r;
            float s = 0.f;
#pragma unroll
            for (int j = 0; j < 4; ++j) {
                int kl = wc * 64 + j * 16 + (lane & 15);
                float v = acc[mi][j][r] + q_lds[b][kl];
                float t = 1.f - 2.f / (__expf(2.f * v) + 1.f);
                s += sc_lds[kl] * t;
            }
            for (int off = 1; off < 16; off <<= 1) s += __shfl_xor(s, off);
            if ((lane & 15) == 0) eng[wc][wr * 64 + mi * 16 + b] = s;
        }
    }
    __syncthreads();
    if (tid < BM) part[(size_t)bn * M_TOT + m0 + tid] = eng[0][tid] + eng[1][tid];
}

// ---------------- kernel 4: reduce partials + mask + softmax over S ----------------
__global__ __launch_bounds__(256) void softmax_kernel(const float* __restrict__ part,
                                                      const int* __restrict__ mask,
                                                      float* __restrict__ out) {
    int b = blockIdx.x;
    int tid = threadIdx.x;
    __shared__ float e_lds[SEQ];
    __shared__ float red[4], red2[4];
    int lane = tid & 63, wid = tid >> 6;
    float lmax = -3.4e38f;
    for (int it = 0; it < SEQ / 256; ++it) {
        int s = it * 256 + tid;
        size_t m = (size_t)s * BATCH + b;
        float e = 0.f;
#pragma unroll
        for (int c = 0; c < NBLK; c++) e += part[(size_t)c * M_TOT + m];
        if (mask[(size_t)b * SEQ + s]) e = -1e12f;
        e_lds[s] = e;
        lmax = fmaxf(lmax, e);
    }
    for (int off = 32; off; off >>= 1) lmax = fmaxf(lmax, __shfl_xor(lmax, off));
    if (lane == 0) red[wid] = lmax;
    __syncthreads();
    float gmax = fmaxf(fmaxf(red[0], red[1]), fmaxf(red[2], red[3]));
    float lsum = 0.f;
    for (int it = 0; it < SEQ / 256; ++it) {
        int s = it * 256 + tid;
        float p = __expf(e_lds[s] - gmax);
        e_lds[s] = p;
        lsum += p;
    }
    for (int off = 32; off; off >>= 1) lsum += __shfl_xor(lsum, off);
    if (lane == 0) red2[wid] = lsum;
    __syncthreads();
    float inv = 1.f / (red2[0] + red2[1] + red2[2] + red2[3]);
    for (int it = 0; it < SEQ / 256; ++it) {
        int s = it * 256 + tid;
        out[(size_t)b * SEQ + s] = e_lds[s] * inv;
    }
}

extern "C" void kernel_launch(void* const* d_in, const int* in_sizes, int n_in,
                              void* d_out, int out_size, void* d_ws, size_t ws_size,
                              hipStream_t stream) {
    const float* hidden   = (const float*)d_in[0];
    const float* enc      = (const float*)d_in[1];
    const int*   seq_mask = (const int*)d_in[2];
    const float* attn_w   = (const float*)d_in[3];
    const float* attn_b   = (const float*)d_in[4];
    const float* score_w  = (const float*)d_in[5];
    float* out = (float*)d_out;

    char* ws = (char*)d_ws;
    float* q = (float*)ws;                                        // 64 KB
    __hip_bfloat16* web = (__hip_bfloat16*)(ws + 65536);          // 2 MB
    float* part = (float*)(ws + 65536 + 2 * 1024 * 1024);         // 1 MB
    __hip_bfloat16* encb = (__hip_bfloat16*)(ws + 65536 + 3 * 1024 * 1024);  // 64 MB

    size_t need = 65536 + (size_t)(3 + 64) * 1024 * 1024;

    if (ws_size >= need) {
        // fast path: pre-convert enc to bf16 (fits L3 -> GEMM re-reads are L3 hits)
        conv_enc<<<dim3((M_TOT * HDIM) / (8 * 256)), dim3(256), 0, stream>>>(enc, encb);
        qk_kernel<<<dim3(HDIM), dim3(256), 0, stream>>>(hidden, attn_w, attn_b, q);
        conv_kernel<<<dim3((HDIM * HDIM) / (8 * 256)), dim3(256), 0, stream>>>(attn_w, web);
        gemm_bf<<<dim3(NBLK, M_TOT / BM), dim3(256), 0, stream>>>(encb, web, q, score_w, part);
        softmax_kernel<<<dim3(BATCH), dim3(256), 0, stream>>>(part, seq_mask, out);
    } else {
        // fallback: round-1 path (fp32 reg-staged GEMM)
        qk_kernel<<<dim3(HDIM), dim3(256), 0, stream>>>(hidden, attn_w, attn_b, q);
        conv_kernel<<<dim3((HDIM * HDIM) / (8 * 256)), dim3(256), 0, stream>>>(attn_w, web);
        gemm_kernel<<<dim3(M_TOT / BM, NBLK), dim3(256), 0, stream>>>(enc, web, q, score_w, part);
        softmax_kernel<<<dim3(BATCH), dim3(256), 0, stream>>>(part, seq_mask, out);
    }
}